// Round 18
// baseline (169.600 us; speedup 1.0000x reference)
//
#include <hip/hip_runtime.h>
#include <hip/hip_bf16.h>

typedef unsigned int u32;
typedef __attribute__((ext_vector_type(8))) short bf16x8;
typedef __attribute__((ext_vector_type(4))) float f32x4;

#define N_NODES 2048
#define INF __builtin_inff()

__device__ __forceinline__ float bflo(u32 u){ return __uint_as_float(u << 16); }
__device__ __forceinline__ float bfhi(u32 u){ return __uint_as_float(u & 0xFFFF0000u); }
__device__ __forceinline__ u32 packbf(float a, float b){
  u32 ua = __float_as_uint(a), ub = __float_as_uint(b);
  u32 ra = (ua + 0x7FFFu + ((ua >> 16) & 1u)) >> 16;
  u32 rb = (ub + 0x7FFFu + ((ub >> 16) & 1u)) >> 16;
  return ra | (rb << 16);
}

__device__ __forceinline__ float dist2(float cx, float cy, float cz,
                                       float jx, float jy, float jz) {
  float dx = cx - jx, dy = cy - jy, dz = cz - jz;
  return fmaf(dz, dz, fmaf(dy, dy, dx * dx));
}

// TRUNCATED key: d^2 bits, low 11 bits = index. Self (d^2 = 0 exactly) is
// the guaranteed global minimum; handled post-merge.
__device__ __forceinline__ float mkk(float d, int j) {
  return __uint_as_float((__float_as_uint(d) & 0xFFFFF800u) | (u32)j);
}

__device__ __forceinline__ void ins8(float (&ad)[8], float v) {
#pragma unroll
  for (int t = 7; t >= 1; --t)
    ad[t] = __builtin_amdgcn_fmed3f(v, ad[t-1], ad[t]);
  ad[0] = fminf(ad[0], v);
}
__device__ __forceinline__ void ins16(float (&ad)[16], float v) {
#pragma unroll
  for (int t = 15; t >= 1; --t)
    ad[t] = __builtin_amdgcn_fmed3f(v, ad[t-1], ad[t]);
  ad[0] = fminf(ad[0], v);
}

// swizzled SoA quad accessor (swizzle spreads bank-groups across g-groups)
__device__ __forceinline__ int swzq(int q){ return q ^ ((q >> 3) & 7); }

// merge 8 sorted-ascending 16-lists across the 8 sublanes (tid^1,^2,^4);
// fully sorted result, identical in all 8 sublanes. XORs stay in-wave.
__device__ __forceinline__ void merge8s(float (&ad)[16], int tid) {
#define CED(I, J) { float lo_ = fminf(ad[I], ad[J]); ad[J] = fmaxf(ad[I], ad[J]); ad[I] = lo_; }
#define CLEAN16 \
  CED(0,8) CED(1,9) CED(2,10) CED(3,11) CED(4,12) CED(5,13) CED(6,14) CED(7,15) \
  CED(0,4) CED(1,5) CED(2,6)  CED(3,7)  CED(8,12) CED(9,13) CED(10,14) CED(11,15) \
  CED(0,2) CED(1,3) CED(4,6)  CED(5,7)  CED(8,10) CED(9,11) CED(12,14) CED(13,15) \
  CED(0,1) CED(2,3) CED(4,5)  CED(6,7)  CED(8,9)  CED(10,11) CED(12,13) CED(14,15)
  float bd[16];
#pragma unroll
  for (int q = 0; q < 16; ++q) bd[q] = __shfl(ad[q], tid ^ 1);
#pragma unroll
  for (int q = 0; q < 16; ++q) ad[q] = fminf(ad[q], bd[15 - q]);
  CLEAN16
#pragma unroll
  for (int q = 0; q < 16; ++q) bd[q] = __shfl(ad[q], tid ^ 2);
#pragma unroll
  for (int q = 0; q < 16; ++q) ad[q] = fminf(ad[q], bd[15 - q]);
  CLEAN16
#pragma unroll
  for (int q = 0; q < 16; ++q) bd[q] = __shfl(ad[q], tid ^ 4);
#pragma unroll
  for (int q = 0; q < 16; ++q) ad[q] = fminf(ad[q], bd[15 - q]);
  CLEAN16
#undef CLEAN16
#undef CED
}

// fast path with self-in-list: merged md[0] = self (guaranteed minimum).
// 16-NN = {md[1..15], c17}. Certificate: depth (myMax >= c18) + truncated
// gap between included c17 and excluded c18.
__device__ __forceinline__ bool node_try8(
    const float (&ad)[8], int tid, int sub, int& j0, int& j1)
{
  const float myMax = ad[7];
  float md[16];
#pragma unroll
  for (int q = 0; q < 8; ++q) md[q] = ad[q];
#pragma unroll
  for (int q = 8; q < 16; ++q) md[q] = __uint_as_float(0x7F000000u);
  merge8s(md, tid);
  const float md15 = md[15];
  float mnext = INF;
#pragma unroll
  for (int q = 7; q >= 0; --q) mnext = (ad[q] > md15) ? ad[q] : mnext;
  float c17 = fminf(mnext, __shfl(mnext, tid ^ 1));
  c17 = fminf(c17, __shfl(c17, tid ^ 2));
  c17 = fminf(c17, __shfl(c17, tid ^ 4));   // rank-17 incl self = 16th NN
  float mnext2 = INF;
#pragma unroll
  for (int q = 7; q >= 0; --q) mnext2 = (ad[q] > c17) ? ad[q] : mnext2;
  float c18 = fminf(mnext2, __shfl(mnext2, tid ^ 1));
  c18 = fminf(c18, __shfl(c18, tid ^ 2));
  c18 = fminf(c18, __shfl(c18, tid ^ 4));   // rank-18 = first excluded
  const u32 t17 = __float_as_uint(c17) & 0xFFFFF800u;
  const u32 t18 = __float_as_uint(c18) & 0xFFFFF800u;
  md[0] = c17;                        // replace self slot with 16th NN
  j0 = (int)(__float_as_uint(md[(sub<<1)+0]) & 0x7FFu);
  j1 = (int)(__float_as_uint(md[(sub<<1)+1]) & 0x7FFu);
  return (myMax >= c18) && (t18 >= t17 + 0x800u);
}

// exact fallback (rare): two-scan exact distances from swizzled SoA LDS.
// nbuf slot private to this 8-lane group (same wave) -> intra-wave lgkmcnt
// ordering suffices; no block barrier (safe under wave-divergent entry).
__device__ __forceinline__ void node_fb8(
    int node, int tid, int sub, int slot,
    float cx, float cy, float cz,
    const float4* xsw, const float4* ysw, const float4* zsw,
    u32 (*nbuf)[16], u32* ncnt, int& j0, int& j1)
{
  float a3[16];
#pragma unroll
  for (int q = 0; q < 16; ++q) a3[q] = INF;
#pragma unroll 1
  for (int it = 0; it < 64; ++it) {
    const int q = (it << 3) + sub;
    const int qs = swzq(q);
    float4 X = xsw[qs], Y = ysw[qs], Z = zsw[qs];
    const int base = q << 2;
    float d0 = (base + 0 == node) ? INF : dist2(cx,cy,cz, X.x,Y.x,Z.x);
    float d1 = (base + 1 == node) ? INF : dist2(cx,cy,cz, X.y,Y.y,Z.y);
    float d2 = (base + 2 == node) ? INF : dist2(cx,cy,cz, X.z,Y.z,Z.z);
    float d3 = (base + 3 == node) ? INF : dist2(cx,cy,cz, X.w,Y.w,Z.w);
    ins16(a3, d0); ins16(a3, d1); ins16(a3, d2); ins16(a3, d3);
  }
  merge8s(a3, tid);
  const float tau = a3[15];
  if (sub == 0) ncnt[slot] = 0;
  asm volatile("s_waitcnt lgkmcnt(0)" ::: "memory");
#pragma unroll 1
  for (int it = 0; it < 64; ++it) {
    const int q = (it << 3) + sub;
    const int qs = swzq(q);
    float4 X = xsw[qs], Y = ysw[qs], Z = zsw[qs];
    const int base = q << 2;
    float d0 = dist2(cx,cy,cz, X.x,Y.x,Z.x);
    float d1 = dist2(cx,cy,cz, X.y,Y.y,Z.y);
    float d2 = dist2(cx,cy,cz, X.z,Y.z,Z.z);
    float d3 = dist2(cx,cy,cz, X.w,Y.w,Z.w);
    if (d0 <= tau && base + 0 != node) { u32 p_ = atomicAdd(&ncnt[slot], 1u); if (p_ < 16u) nbuf[slot][p_] = (u32)(base + 0); }
    if (d1 <= tau && base + 1 != node) { u32 p_ = atomicAdd(&ncnt[slot], 1u); if (p_ < 16u) nbuf[slot][p_] = (u32)(base + 1); }
    if (d2 <= tau && base + 2 != node) { u32 p_ = atomicAdd(&ncnt[slot], 1u); if (p_ < 16u) nbuf[slot][p_] = (u32)(base + 2); }
    if (d3 <= tau && base + 3 != node) { u32 p_ = atomicAdd(&ncnt[slot], 1u); if (p_ < 16u) nbuf[slot][p_] = (u32)(base + 3); }
  }
  asm volatile("s_waitcnt lgkmcnt(0)" ::: "memory");
  j0 = (int)nbuf[slot][(sub << 1) + 0];
  j1 = (int)nbuf[slot][(sub << 1) + 1];
}

// ---------------------------------------------------------------------------
// K1: exact KNN (K=16) + GCN layer 1 fused. 1024 blocks x 512 thr (8 waves);
// block = 64 nodes, one node per 8-lane group. ROTATED COVERAGE: lane (g,s)
// reads quad (64s+8g+i) mod 512 -> all 64 lanes read DISTINCT quads each
// iteration (still a per-node bijection over all 2048 candidates), stored
// as XOR-swizzled SoA. 3 ds_read_b128 now serve 256 evals (vs 6 per 64) --
// 8x fewer LDS instructions, removing the LDS-pipe oversubscription that
// pinned duty at ~54% across rounds 7-17.
// ---------------------------------------------------------------------------
__global__ __launch_bounds__(512) void k1_knn_l1(
    const float* __restrict__ coords, const float* __restrict__ W1,
    const float* __restrict__ b1, int* __restrict__ nbr, u32* __restrict__ x1)
{
  __shared__ float4 xsw[512], ysw[512], zsw[512];  // 24 KB swizzled SoA quads
  __shared__ u32    nbuf[64][16];                  // 4 KB fallback
  __shared__ u32    ncnt[64];
  __shared__ float  w1s[192];
  __shared__ float  b1s[64];
  const int tid   = threadIdx.x;
  const int s     = blockIdx.x >> 5;    // 32 blocks per sample
  const int chunk = blockIdx.x & 31;    // 64-node chunk
  const float* cg = coords + (size_t)s * (N_NODES * 3);
  {
    // thread t builds quad t: transpose AoS -> SoA quads, swizzled store
    const float4* src = (const float4*)(cg + 12 * tid);
    float4 v0 = src[0], v1 = src[1], v2 = src[2];
    const int qs = swzq(tid);
    xsw[qs] = make_float4(v0.x, v0.w, v1.z, v2.y);
    ysw[qs] = make_float4(v0.y, v1.x, v1.w, v2.z);
    zsw[qs] = make_float4(v0.z, v1.y, v2.x, v2.w);
  }
  if (tid < 192) w1s[tid] = W1[tid];
  if (tid < 64)  b1s[tid] = b1[tid];
  __syncthreads();

  const int ln   = tid >> 3;            // node slot 0..63
  const int g    = ln & 7;              // node-in-wave 0..7
  const int sub  = tid & 7;             // sublane 0..7
  const int node = (chunk << 6) + ln;
  float cx, cy, cz;
  {
    const int sq = node >> 2, se = node & 3, sqs = swzq(sq);
    cx = ((const float*)&xsw[sqs])[se];
    cy = ((const float*)&ysw[sqs])[se];
    cz = ((const float*)&zsw[sqs])[se];
  }

  const int qbase = (sub << 6) + (g << 3);   // 64s + 8g

  float ad[8];
#pragma unroll
  for (int q = 0; q < 8; ++q) ad[q] = INF;

#define LOAD3(PX,PY,PZ, I) {                                              \
    const int q_ = (qbase + (I)) & 511;                                   \
    const int qs_ = swzq(q_);                                             \
    PX = xsw[qs_]; PY = ysw[qs_]; PZ = zsw[qs_]; }

#define BODY(PX,PY,PZ, I) {                                               \
    const int jb_ = ((qbase + (I)) & 511) << 2;                           \
    ins8(ad, mkk(dist2(cx,cy,cz, PX.x,PY.x,PZ.x), jb_+0));                \
    ins8(ad, mkk(dist2(cx,cy,cz, PX.y,PY.y,PZ.y), jb_+1));                \
    ins8(ad, mkk(dist2(cx,cy,cz, PX.z,PY.z,PZ.z), jb_+2));                \
    ins8(ad, mkk(dist2(cx,cy,cz, PX.w,PY.w,PZ.w), jb_+3)); }

  {
    float4 AX, AY, AZ, BX, BY, BZ;
    LOAD3(AX,AY,AZ, 0)
#pragma unroll 1
    for (int i = 0; i < 64; i += 2) {
      LOAD3(BX,BY,BZ, i + 1)
      BODY (AX,AY,AZ, i)
      LOAD3(AX,AY,AZ, (i + 2) & 63)   // last prefetch wraps (unused)
      BODY (BX,BY,BZ, i + 1)
    }
  }
#undef LOAD3
#undef BODY

  int j0, j1;
  const bool ok = node_try8(ad, tid, sub, j0, j1);
  if (!__all((int)ok)) {
    node_fb8(node, tid, sub, ln, cx, cy, cz, xsw, ysw, zsw, nbuf, ncnt, j0, j1);
  }

  const size_t gnode = ((size_t)s << 11) + node;
  *(int2*)(nbr + gnode * 16 + (sub << 1)) = make_int2(j0, j1);

  // ---- layer 1: mean over {self + 16 nbrs}, 3x64 matmul + ReLU ----
  float sx, sy, sz;
  if (sub == 0) { sx = cx; sy = cy; sz = cz; } else { sx = 0.f; sy = 0.f; sz = 0.f; }
  {
    const int q0 = j0 >> 2, e0 = j0 & 3, qs0 = swzq(q0);
    const int q1 = j1 >> 2, e1 = j1 & 3, qs1 = swzq(q1);
    sx += ((const float*)&xsw[qs0])[e0] + ((const float*)&xsw[qs1])[e1];
    sy += ((const float*)&ysw[qs0])[e0] + ((const float*)&ysw[qs1])[e1];
    sz += ((const float*)&zsw[qs0])[e0] + ((const float*)&zsw[qs1])[e1];
  }
  sx += __shfl_xor(sx, 1); sx += __shfl_xor(sx, 2); sx += __shfl_xor(sx, 4);
  sy += __shfl_xor(sy, 1); sy += __shfl_xor(sy, 2); sy += __shfl_xor(sy, 4);
  sz += __shfl_xor(sz, 1); sz += __shfl_xor(sz, 2); sz += __shfl_xor(sz, 4);
  const float inv = 1.0f / 17.0f;
  float mx = sx * inv, my = sy * inv, mz = sz * inv;

  u32 pk[4];
#pragma unroll
  for (int oo = 0; oo < 8; oo += 2) {
    const int o = (sub << 3) + oo;
    float v0 = fmaf(mz, w1s[128+o],   fmaf(my, w1s[64+o],   fmaf(mx, w1s[o],   b1s[o])));
    float v1 = fmaf(mz, w1s[128+o+1], fmaf(my, w1s[64+o+1], fmaf(mx, w1s[o+1], b1s[o+1])));
    pk[oo >> 1] = packbf(fmaxf(v0, 0.0f), fmaxf(v1, 0.0f));
  }
  *(uint4*)(x1 + gnode * 32 + (sub << 2)) = make_uint4(pk[0], pk[1], pk[2], pk[3]);
}

// ---------------------------------------------------------------------------
// K2: gather-mean of x1 over {nbr,self} -> bf16 A-tile (LDS, swizzled) ->
// MFMA GEMM [128 x 64] @ [64 x 128], hi/lo-split bf16 weights -> ReLU -> x2.
// ---------------------------------------------------------------------------
__global__ __launch_bounds__(256) void k2_gcn2(
    const u32* __restrict__ x1, const int* __restrict__ nbr,
    const float* __restrict__ W2, const float* __restrict__ b2,
    u32* __restrict__ x2)
{
  __shared__ uint4 AldsV[1024];   // 16 KB
  __shared__ uint4 BhiV[1024];    // 16 KB
  __shared__ uint4 BloV[1024];    // 16 KB
  char* Alds = (char*)AldsV; char* Bhi = (char*)BhiV; char* Blo = (char*)BloV;
  const int tid   = threadIdx.x;
  const int node0 = blockIdx.x << 7;

#pragma unroll
  for (int i = 0; i < 32; ++i) {
    int e = tid + (i << 8);
    int k = e >> 7, n = e & 127;
    float w = W2[e];
    u32 hb = packbf(w, 0.0f) & 0xFFFFu;
    float whi = __uint_as_float(hb << 16);
    u32 lb = packbf(w - whi, 0.0f) & 0xFFFFu;
    int byte = n * 128 + ((2 * k) ^ ((n & 7) << 4));
    *(unsigned short*)(Bhi + byte) = (unsigned short)hb;
    *(unsigned short*)(Blo + byte) = (unsigned short)lb;
  }

  {
    const int r = tid >> 1, half = tid & 1;
    const size_t gnode = (size_t)node0 + r;
    const u32* selfp = x1 + gnode * 32 + half * 16;
    const u32* x1s   = x1 + ((gnode >> 11) << 11) * 32;
    const int* nb    = nbr + gnode * 16;
    float a[32];
#pragma unroll
    for (int q = 0; q < 4; ++q) {
      uint4 v = *(const uint4*)(selfp + (q << 2));
      a[8*q+0] = bflo(v.x); a[8*q+1] = bfhi(v.x);
      a[8*q+2] = bflo(v.y); a[8*q+3] = bfhi(v.y);
      a[8*q+4] = bflo(v.z); a[8*q+5] = bfhi(v.z);
      a[8*q+6] = bflo(v.w); a[8*q+7] = bfhi(v.w);
    }
#pragma unroll
    for (int t = 0; t < 16; ++t) {
      const u32* rp = x1s + (size_t)nb[t] * 32 + half * 16;
#pragma unroll
      for (int q = 0; q < 4; ++q) {
        uint4 v = *(const uint4*)(rp + (q << 2));
        a[8*q+0] += bflo(v.x); a[8*q+1] += bfhi(v.x);
        a[8*q+2] += bflo(v.y); a[8*q+3] += bfhi(v.y);
        a[8*q+4] += bflo(v.z); a[8*q+5] += bfhi(v.z);
        a[8*q+6] += bflo(v.w); a[8*q+7] += bfhi(v.w);
      }
    }
    const float inv = 1.0f / 17.0f;
    u32 pk[16];
#pragma unroll
    for (int j = 0; j < 16; ++j)
      pk[j] = packbf(a[2*j] * inv, a[2*j+1] * inv);
#pragma unroll
    for (int q = 0; q < 4; ++q) {
      int byte = r * 128 + ((((half << 6) + (q << 4))) ^ ((r & 7) << 4));
      *(uint4*)(Alds + byte) = make_uint4(pk[4*q], pk[4*q+1], pk[4*q+2], pk[4*q+3]);
    }
  }
  __syncthreads();

  const int lane = tid & 63, wv = tid >> 6;
  const int cl = lane & 15, kg = lane >> 4;

  f32x4 acc[2][8];
#pragma unroll
  for (int rt = 0; rt < 2; ++rt)
#pragma unroll
    for (int ct = 0; ct < 8; ++ct) {
      float bv = b2[(ct << 4) + cl];
      acc[rt][ct] = (f32x4){bv, bv, bv, bv};
    }

#pragma unroll
  for (int ks = 0; ks < 2; ++ks) {
    const int kb = (ks << 6) + (kg << 4);
    bf16x8 af[2];
#pragma unroll
    for (int rt = 0; rt < 2; ++rt) {
      int row = (wv << 5) + (rt << 4) + cl;
      af[rt] = *(const bf16x8*)(Alds + row * 128 + (kb ^ ((row & 7) << 4)));
    }
#pragma unroll
    for (int ct = 0; ct < 8; ++ct) {
      int n = (ct << 4) + cl;
      int byte = n * 128 + (kb ^ ((n & 7) << 4));
      bf16x8 bh = *(const bf16x8*)(Bhi + byte);
      bf16x8 bl = *(const bf16x8*)(Blo + byte);
#pragma unroll
      for (int rt = 0; rt < 2; ++rt) {
        acc[rt][ct] = __builtin_amdgcn_mfma_f32_16x16x32_bf16(af[rt], bh, acc[rt][ct], 0, 0, 0);
        acc[rt][ct] = __builtin_amdgcn_mfma_f32_16x16x32_bf16(af[rt], bl, acc[rt][ct], 0, 0, 0);
      }
    }
  }

  unsigned short* x2h = (unsigned short*)x2;
#pragma unroll
  for (int rt = 0; rt < 2; ++rt)
#pragma unroll
    for (int ct = 0; ct < 8; ++ct) {
      int colg = (ct << 4) + cl;
      int nr0  = node0 + (wv << 5) + (rt << 4) + (kg << 2);
#pragma unroll
      for (int r = 0; r < 4; ++r) {
        float v = fmaxf(acc[rt][ct][r], 0.0f);
        x2h[(size_t)(nr0 + r) * 128 + colg] = (unsigned short)(packbf(v, 0.0f) & 0xFFFFu);
      }
    }
}

// ---------------------------------------------------------------------------
// K3: final linear 128->128 via MFMA, hi/lo-split weights, f32 out.
// ---------------------------------------------------------------------------
__global__ __launch_bounds__(256) void k3_final(
    const u32* __restrict__ x2, const float* __restrict__ Wf,
    const float* __restrict__ bfv, float* __restrict__ out)
{
  __shared__ uint4 AldsV[2048];   // 32 KB
  __shared__ uint4 BhiV[1024];    // 16 KB
  __shared__ uint4 BloV[1024];
  char* Alds = (char*)AldsV; char* Bhi = (char*)BhiV; char* Blo = (char*)BloV;
  const int tid   = threadIdx.x;
  const int node0 = (blockIdx.x >> 1) << 7;
  const int ch0   = (blockIdx.x & 1) << 6;

#pragma unroll
  for (int i = 0; i < 32; ++i) {
    int e = tid + (i << 8);
    int k = e >> 6, n = e & 63;
    float w = Wf[k * 128 + ch0 + n];
    u32 hb = packbf(w, 0.0f) & 0xFFFFu;
    float whi = __uint_as_float(hb << 16);
    u32 lb = packbf(w - whi, 0.0f) & 0xFFFFu;
    int byte = n * 256 + ((2 * k) ^ ((n & 15) << 4));
    *(unsigned short*)(Bhi + byte) = (unsigned short)hb;
    *(unsigned short*)(Blo + byte) = (unsigned short)lb;
  }

  {
    const int r = tid >> 1, half = tid & 1;
    const u32* src = x2 + (size_t)(node0 + r) * 64 + half * 32;
#pragma unroll
    for (int q = 0; q < 8; ++q) {
      uint4 v = *(const uint4*)(src + (q << 2));
      int byte = r * 256 + ((((half << 7) + (q << 4))) ^ ((r & 15) << 4));
      *(uint4*)(Alds + byte) = v;
    }
  }
  __syncthreads();

  const int lane = tid & 63, wv = tid >> 6;
  const int cl = lane & 15, kg = lane >> 4;

  f32x4 acc[2][4];
#pragma unroll
  for (int rt = 0; rt < 2; ++rt)
#pragma unroll
    for (int ct = 0; ct < 4; ++ct) {
      float bv = bfv[ch0 + (ct << 4) + cl];
      acc[rt][ct] = (f32x4){bv, bv, bv, bv};
    }

#pragma unroll
  for (int ks = 0; ks < 4; ++ks) {
    const int kb = (ks << 6) + (kg << 4);
    bf16x8 af[2];
#pragma unroll
    for (int rt = 0; rt < 2; ++rt) {
      int row = (wv << 5) + (rt << 4) + cl;
      af[rt] = *(const bf16x8*)(Alds + row * 256 + (kb ^ ((row & 15) << 4)));
    }
#pragma unroll
    for (int ct = 0; ct < 4; ++ct) {
      int n = (ct << 4) + cl;
      int byte = n * 256 + (kb ^ ((n & 15) << 4));
      bf16x8 bh = *(const bf16x8*)(Bhi + byte);
      bf16x8 bl = *(const bf16x8*)(Blo + byte);
#pragma unroll
      for (int rt = 0; rt < 2; ++rt) {
        acc[rt][ct] = __builtin_amdgcn_mfma_f32_16x16x32_bf16(af[rt], bh, acc[rt][ct], 0, 0, 0);
        acc[rt][ct] = __builtin_amdgcn_mfma_f32_16x16x32_bf16(af[rt], bl, acc[rt][ct], 0, 0, 0);
      }
    }
  }

#pragma unroll
  for (int rt = 0; rt < 2; ++rt)
#pragma unroll
    for (int ct = 0; ct < 4; ++ct) {
      int col = ch0 + (ct << 4) + cl;
      int nr0 = node0 + (wv << 5) + (rt << 4) + (kg << 2);
#pragma unroll
      for (int r = 0; r < 4; ++r)
        out[(size_t)(nr0 + r) * 128 + col] = acc[rt][ct][r];
    }
}

extern "C" void kernel_launch(void* const* d_in, const int* in_sizes, int n_in,
                              void* d_out, int out_size, void* d_ws, size_t ws_size,
                              hipStream_t stream) {
  const float* coords = (const float*)d_in[0];
  const float* W1 = (const float*)d_in[1];
  const float* b1 = (const float*)d_in[2];
  const float* W2 = (const float*)d_in[3];
  const float* b2 = (const float*)d_in[4];
  const float* Wf = (const float*)d_in[5];
  const float* bf = (const float*)d_in[6];
  float* out = (float*)d_out;

  char* ws = (char*)d_ws;
  int* nbr = (int*)ws;                                  //  4 MB: [32,2048,16] i32
  u32* x1  = (u32*)(ws + (size_t)4  * 1024 * 1024);     //  8 MB: [32,2048,64] bf16
  u32* x2  = (u32*)(ws + (size_t)12 * 1024 * 1024);     // 16 MB: [65536,128] bf16

  k1_knn_l1<<<1024, 512, 0, stream>>>(coords, W1, b1, nbr, x1);
  k2_gcn2  <<< 512, 256, 0, stream>>>(x1, nbr, W2, b2, x2);
  k3_final <<<1024, 256, 0, stream>>>(x2, Wf, bf, out);
}

// Round 19
// 156.126 us; speedup vs baseline: 1.0863x; 1.0863x over previous
//
#include <hip/hip_runtime.h>
#include <hip/hip_bf16.h>

typedef unsigned int u32;
typedef __attribute__((ext_vector_type(8))) short bf16x8;
typedef __attribute__((ext_vector_type(4))) float f32x4;

#define N_NODES 2048
#define INF __builtin_inff()

__device__ __forceinline__ float bflo(u32 u){ return __uint_as_float(u << 16); }
__device__ __forceinline__ float bfhi(u32 u){ return __uint_as_float(u & 0xFFFF0000u); }
__device__ __forceinline__ u32 packbf(float a, float b){
  u32 ua = __float_as_uint(a), ub = __float_as_uint(b);
  u32 ra = (ua + 0x7FFFu + ((ua >> 16) & 1u)) >> 16;
  u32 rb = (ub + 0x7FFFu + ((ub >> 16) & 1u)) >> 16;
  return ra | (rb << 16);
}

__device__ __forceinline__ float dist2(float cx, float cy, float cz,
                                       float jx, float jy, float jz) {
  float dx = cx - jx, dy = cy - jy, dz = cz - jz;
  return fmaf(dz, dz, fmaf(dy, dy, dx * dx));
}

// TRUNCATED key: d^2 bits, low 11 bits = index. Self (d^2 = 0 exactly) is
// the guaranteed global minimum; handled post-merge.
__device__ __forceinline__ float mkk(float d, int j) {
  return __uint_as_float((__float_as_uint(d) & 0xFFFFF800u) | (u32)j);
}

__device__ __forceinline__ void ins6(float (&ad)[6], float v) {
#pragma unroll
  for (int t = 5; t >= 1; --t)
    ad[t] = __builtin_amdgcn_fmed3f(v, ad[t-1], ad[t]);
  ad[0] = fminf(ad[0], v);
}
__device__ __forceinline__ void ins8(float (&ad)[8], float v) {
#pragma unroll
  for (int t = 7; t >= 1; --t)
    ad[t] = __builtin_amdgcn_fmed3f(v, ad[t-1], ad[t]);
  ad[0] = fminf(ad[0], v);
}
__device__ __forceinline__ void ins16(float (&ad)[16], float v) {
#pragma unroll
  for (int t = 15; t >= 1; --t)
    ad[t] = __builtin_amdgcn_fmed3f(v, ad[t-1], ad[t]);
  ad[0] = fminf(ad[0], v);
}

// merge 8 sorted-ascending 16-lists across the 8 sublanes (tid^1,^2,^4);
// fully sorted result, identical in all 8 sublanes.
__device__ __forceinline__ void merge8s(float (&ad)[16], int tid) {
#define CED(I, J) { float lo_ = fminf(ad[I], ad[J]); ad[J] = fmaxf(ad[I], ad[J]); ad[I] = lo_; }
#define CLEAN16 \
  CED(0,8) CED(1,9) CED(2,10) CED(3,11) CED(4,12) CED(5,13) CED(6,14) CED(7,15) \
  CED(0,4) CED(1,5) CED(2,6)  CED(3,7)  CED(8,12) CED(9,13) CED(10,14) CED(11,15) \
  CED(0,2) CED(1,3) CED(4,6)  CED(5,7)  CED(8,10) CED(9,11) CED(12,14) CED(13,15) \
  CED(0,1) CED(2,3) CED(4,5)  CED(6,7)  CED(8,9)  CED(10,11) CED(12,13) CED(14,15)
  float bd[16];
#pragma unroll
  for (int q = 0; q < 16; ++q) bd[q] = __shfl(ad[q], tid ^ 1);
#pragma unroll
  for (int q = 0; q < 16; ++q) ad[q] = fminf(ad[q], bd[15 - q]);
  CLEAN16
#pragma unroll
  for (int q = 0; q < 16; ++q) bd[q] = __shfl(ad[q], tid ^ 2);
#pragma unroll
  for (int q = 0; q < 16; ++q) ad[q] = fminf(ad[q], bd[15 - q]);
  CLEAN16
#pragma unroll
  for (int q = 0; q < 16; ++q) bd[q] = __shfl(ad[q], tid ^ 4);
#pragma unroll
  for (int q = 0; q < 16; ++q) ad[q] = fminf(ad[q], bd[15 - q]);
  CLEAN16
#undef CLEAN16
#undef CED
}

// fast path with self-in-list: merged md[0] = self (guaranteed minimum).
// 16-NN = {md[1..15], c17}. Certificate: depth checks (ad7 >= c18 AND every
// chain's max-kept mn4 >= c18) + truncated gap between c17 and c18.
__device__ __forceinline__ bool node_try8(
    const float (&ad)[8], float mn4, int tid, int sub, int& j0, int& j1)
{
  const float myMax = ad[7];
  float md[16];
#pragma unroll
  for (int q = 0; q < 8; ++q) md[q] = ad[q];
#pragma unroll
  for (int q = 8; q < 16; ++q) md[q] = __uint_as_float(0x7F000000u);
  merge8s(md, tid);
  const float md15 = md[15];
  float mnext = INF;
#pragma unroll
  for (int q = 7; q >= 0; --q) mnext = (ad[q] > md15) ? ad[q] : mnext;
  float c17 = fminf(mnext, __shfl(mnext, tid ^ 1));
  c17 = fminf(c17, __shfl(c17, tid ^ 2));
  c17 = fminf(c17, __shfl(c17, tid ^ 4));   // rank-17 incl self = 16th NN
  float mnext2 = INF;
#pragma unroll
  for (int q = 7; q >= 0; --q) mnext2 = (ad[q] > c17) ? ad[q] : mnext2;
  float c18 = fminf(mnext2, __shfl(mnext2, tid ^ 1));
  c18 = fminf(c18, __shfl(c18, tid ^ 2));
  c18 = fminf(c18, __shfl(c18, tid ^ 4));   // rank-18 = first excluded
  const u32 t17 = __float_as_uint(c17) & 0xFFFFF800u;
  const u32 t18 = __float_as_uint(c18) & 0xFFFFF800u;
  md[0] = c17;                        // replace self slot with 16th NN
  j0 = (int)(__float_as_uint(md[(sub<<1)+0]) & 0x7FFu);
  j1 = (int)(__float_as_uint(md[(sub<<1)+1]) & 0x7FFu);
  return (myMax >= c18) && (mn4 >= c18) && (t18 >= t17 + 0x800u);
}

// exact fallback (rare): two-scan exact distances from LDS. nbuf slot is
// private to this 8-lane group (same wave) -> intra-wave lgkmcnt ordering
// suffices; no block barrier (safe under wave-divergent entry).
__device__ __forceinline__ void node_fb8(
    int node, int tid, int sub, int slot,
    float cx, float cy, float cz, const float* cs,
    u32 (*nbuf)[16], u32* ncnt, int& j0, int& j1)
{
  float a3[16];
#pragma unroll
  for (int q = 0; q < 16; ++q) a3[q] = INF;
#pragma unroll 1
  for (int it = 0; it < 64; ++it) {
    const int v4 = (it << 3) + sub;
    const float4* p = (const float4*)(cs + v4 * 12);
    float4 p0 = p[0], p1 = p[1], p2 = p[2];
    const int base = v4 << 2;
    float d0 = (base + 0 == node) ? INF : dist2(cx,cy,cz, p0.x,p0.y,p0.z);
    float d1 = (base + 1 == node) ? INF : dist2(cx,cy,cz, p0.w,p1.x,p1.y);
    float d2 = (base + 2 == node) ? INF : dist2(cx,cy,cz, p1.z,p1.w,p2.x);
    float d3 = (base + 3 == node) ? INF : dist2(cx,cy,cz, p2.y,p2.z,p2.w);
    ins16(a3, d0); ins16(a3, d1); ins16(a3, d2); ins16(a3, d3);
  }
  merge8s(a3, tid);
  const float tau = a3[15];
  if (sub == 0) ncnt[slot] = 0;
  asm volatile("s_waitcnt lgkmcnt(0)" ::: "memory");
#pragma unroll 1
  for (int it = 0; it < 64; ++it) {
    const int v4 = (it << 3) + sub;
    const float4* p = (const float4*)(cs + v4 * 12);
    float4 p0 = p[0], p1 = p[1], p2 = p[2];
    const int base = v4 << 2;
    float d0 = dist2(cx,cy,cz, p0.x,p0.y,p0.z);
    float d1 = dist2(cx,cy,cz, p0.w,p1.x,p1.y);
    float d2 = dist2(cx,cy,cz, p1.z,p1.w,p2.x);
    float d3 = dist2(cx,cy,cz, p2.y,p2.z,p2.w);
    if (d0 <= tau && base + 0 != node) { u32 p_ = atomicAdd(&ncnt[slot], 1u); if (p_ < 16u) nbuf[slot][p_] = (u32)(base + 0); }
    if (d1 <= tau && base + 1 != node) { u32 p_ = atomicAdd(&ncnt[slot], 1u); if (p_ < 16u) nbuf[slot][p_] = (u32)(base + 1); }
    if (d2 <= tau && base + 2 != node) { u32 p_ = atomicAdd(&ncnt[slot], 1u); if (p_ < 16u) nbuf[slot][p_] = (u32)(base + 2); }
    if (d3 <= tau && base + 3 != node) { u32 p_ = atomicAdd(&ncnt[slot], 1u); if (p_ < 16u) nbuf[slot][p_] = (u32)(base + 3); }
  }
  asm volatile("s_waitcnt lgkmcnt(0)" ::: "memory");
  j0 = (int)nbuf[slot][(sub << 1) + 0];
  j1 = (int)nbuf[slot][(sub << 1) + 1];
}

// ---------------------------------------------------------------------------
// K1: exact KNN (K=16) + GCN layer 1 fused. 2048 blocks x 256 thr; block =
// 32 nodes, 8 sublanes/node, LDS-staged coords, ping-pong prefetch (r14).
// NEW: each lane runs FOUR independent depth-6 insert chains (candidates
// round-robin across chains) -> 4-way ILP on the med3 dependency chain that
// pinned per-wave duty at ~27% across rounds 7-18. 24 kept keys merge
// in-lane into the sorted ad[8] feeding the unchanged merge/certificate.
// ---------------------------------------------------------------------------
__global__ __launch_bounds__(256) void k1_knn_l1(
    const float* __restrict__ coords, const float* __restrict__ W1,
    const float* __restrict__ b1, int* __restrict__ nbr, u32* __restrict__ x1)
{
  __shared__ float ldsc[N_NODES * 3];   // 24 KB coords, AoS
  __shared__ u32   nbuf[32][16];        // fallback
  __shared__ u32   ncnt[32];
  __shared__ float w1s[192];
  __shared__ float b1s[64];
  const int tid   = threadIdx.x;
  const int s     = blockIdx.x >> 6;
  const int chunk = blockIdx.x & 63;
  const float* cg = coords + (size_t)s * (N_NODES * 3);
  {
    const float4* src = (const float4*)cg;
    float4* dst = (float4*)ldsc;
#pragma unroll
    for (int q = 0; q < 6; ++q) dst[tid + (q << 8)] = src[tid + (q << 8)];
  }
  if (tid < 192) w1s[tid] = W1[tid];
  if (tid < 64)  b1s[tid] = b1[tid];
  __syncthreads();

  const int ln   = tid >> 3;          // node slot 0..31
  const int sub  = tid & 7;           // sublane 0..7
  const int node = (chunk << 5) + ln;
  const float cx = ldsc[3*node], cy = ldsc[3*node+1], cz = ldsc[3*node+2];

  float c0[6], c1[6], c2[6], c3[6];   // 4 independent depth-6 chains
#pragma unroll
  for (int q = 0; q < 6; ++q) { c0[q] = INF; c1[q] = INF; c2[q] = INF; c3[q] = INF; }

#define LOAD6(P0,P1,P2,P3,P4,P5, ITV) {                                   \
    const int v4a_ = ((ITV) << 4) + sub;                                  \
    const float4* pa_ = (const float4*)(ldsc + v4a_ * 12);                \
    const float4* pb_ = (const float4*)(ldsc + (v4a_ + 8) * 12);          \
    P0 = pa_[0]; P1 = pa_[1]; P2 = pa_[2];                                \
    P3 = pb_[0]; P4 = pb_[1]; P5 = pb_[2]; }

#define BODY(P0,P1,P2,P3,P4,P5, ITV) {                                    \
    const int ba_ = (((ITV) << 4) + sub) << 2, bb_ = ba_ + 32;            \
    ins6(c0, mkk(dist2(cx,cy,cz, P0.x,P0.y,P0.z),   ba_+0));              \
    ins6(c1, mkk(dist2(cx,cy,cz, P0.w,P1.x,P1.y),   ba_+1));              \
    ins6(c2, mkk(dist2(cx,cy,cz, P1.z,P1.w,P2.x),   ba_+2));              \
    ins6(c3, mkk(dist2(cx,cy,cz, P2.y,P2.z,P2.w),   ba_+3));              \
    ins6(c0, mkk(dist2(cx,cy,cz, P3.x,P3.y,P3.z),   bb_+0));              \
    ins6(c1, mkk(dist2(cx,cy,cz, P3.w,P4.x,P4.y),   bb_+1));              \
    ins6(c2, mkk(dist2(cx,cy,cz, P4.z,P4.w,P5.x),   bb_+2));              \
    ins6(c3, mkk(dist2(cx,cy,cz, P5.y,P5.z,P5.w),   bb_+3)); }

  {
    float4 A0, A1, A2, A3, A4, A5, B0, B1, B2, B3, B4, B5;
    LOAD6(A0,A1,A2,A3,A4,A5, 0)
#pragma unroll 1
    for (int it = 0; it < 32; it += 2) {
      LOAD6(B0,B1,B2,B3,B4,B5, it + 1)
      BODY (A0,A1,A2,A3,A4,A5, it)
      LOAD6(A0,A1,A2,A3,A4,A5, (it + 2) & 31)   // last prefetch wraps (unused)
      BODY (B0,B1,B2,B3,B4,B5, it + 1)
    }
  }
#undef LOAD6
#undef BODY

  // in-lane merge of the 24 kept keys -> sorted-ascending 8 smallest
  float ad[8];
#pragma unroll
  for (int q = 0; q < 8; ++q) ad[q] = INF;
#pragma unroll
  for (int q = 0; q < 6; ++q) {
    ins8(ad, c0[q]); ins8(ad, c1[q]); ins8(ad, c2[q]); ins8(ad, c3[q]);
  }
  const float mn4 = fminf(fminf(c0[5], c1[5]), fminf(c2[5], c3[5]));

  int j0, j1;
  const bool ok = node_try8(ad, mn4, tid, sub, j0, j1);
  if (!__all((int)ok)) {
    node_fb8(node, tid, sub, ln, cx, cy, cz, ldsc, nbuf, ncnt, j0, j1);
  }

  const size_t gnode = ((size_t)s << 11) + node;
  *(int2*)(nbr + gnode * 16 + (sub << 1)) = make_int2(j0, j1);

  // ---- layer 1: mean over {self + 16 nbrs}, 3x64 matmul + ReLU ----
  float sx, sy, sz;
  if (sub == 0) { sx = cx; sy = cy; sz = cz; } else { sx = 0.f; sy = 0.f; sz = 0.f; }
  sx += ldsc[3*j0]   + ldsc[3*j1];
  sy += ldsc[3*j0+1] + ldsc[3*j1+1];
  sz += ldsc[3*j0+2] + ldsc[3*j1+2];
  sx += __shfl_xor(sx, 1); sx += __shfl_xor(sx, 2); sx += __shfl_xor(sx, 4);
  sy += __shfl_xor(sy, 1); sy += __shfl_xor(sy, 2); sy += __shfl_xor(sy, 4);
  sz += __shfl_xor(sz, 1); sz += __shfl_xor(sz, 2); sz += __shfl_xor(sz, 4);
  const float inv = 1.0f / 17.0f;
  float mx = sx * inv, my = sy * inv, mz = sz * inv;

  u32 pk[4];
#pragma unroll
  for (int oo = 0; oo < 8; oo += 2) {
    const int o = (sub << 3) + oo;
    float v0 = fmaf(mz, w1s[128+o],   fmaf(my, w1s[64+o],   fmaf(mx, w1s[o],   b1s[o])));
    float v1 = fmaf(mz, w1s[128+o+1], fmaf(my, w1s[64+o+1], fmaf(mx, w1s[o+1], b1s[o+1])));
    pk[oo >> 1] = packbf(fmaxf(v0, 0.0f), fmaxf(v1, 0.0f));
  }
  *(uint4*)(x1 + gnode * 32 + (sub << 2)) = make_uint4(pk[0], pk[1], pk[2], pk[3]);
}

// ---------------------------------------------------------------------------
// K2: gather-mean of x1 over {nbr,self} -> bf16 A-tile (LDS, swizzled) ->
// MFMA GEMM [128 x 64] @ [64 x 128], hi/lo-split bf16 weights -> ReLU -> x2.
// ---------------------------------------------------------------------------
__global__ __launch_bounds__(256) void k2_gcn2(
    const u32* __restrict__ x1, const int* __restrict__ nbr,
    const float* __restrict__ W2, const float* __restrict__ b2,
    u32* __restrict__ x2)
{
  __shared__ uint4 AldsV[1024];   // 16 KB
  __shared__ uint4 BhiV[1024];    // 16 KB
  __shared__ uint4 BloV[1024];    // 16 KB
  char* Alds = (char*)AldsV; char* Bhi = (char*)BhiV; char* Blo = (char*)BloV;
  const int tid   = threadIdx.x;
  const int node0 = blockIdx.x << 7;

#pragma unroll
  for (int i = 0; i < 32; ++i) {
    int e = tid + (i << 8);
    int k = e >> 7, n = e & 127;
    float w = W2[e];
    u32 hb = packbf(w, 0.0f) & 0xFFFFu;
    float whi = __uint_as_float(hb << 16);
    u32 lb = packbf(w - whi, 0.0f) & 0xFFFFu;
    int byte = n * 128 + ((2 * k) ^ ((n & 7) << 4));
    *(unsigned short*)(Bhi + byte) = (unsigned short)hb;
    *(unsigned short*)(Blo + byte) = (unsigned short)lb;
  }

  {
    const int r = tid >> 1, half = tid & 1;
    const size_t gnode = (size_t)node0 + r;
    const u32* selfp = x1 + gnode * 32 + half * 16;
    const u32* x1s   = x1 + ((gnode >> 11) << 11) * 32;
    const int* nb    = nbr + gnode * 16;
    float a[32];
#pragma unroll
    for (int q = 0; q < 4; ++q) {
      uint4 v = *(const uint4*)(selfp + (q << 2));
      a[8*q+0] = bflo(v.x); a[8*q+1] = bfhi(v.x);
      a[8*q+2] = bflo(v.y); a[8*q+3] = bfhi(v.y);
      a[8*q+4] = bflo(v.z); a[8*q+5] = bfhi(v.z);
      a[8*q+6] = bflo(v.w); a[8*q+7] = bfhi(v.w);
    }
#pragma unroll
    for (int t = 0; t < 16; ++t) {
      const u32* rp = x1s + (size_t)nb[t] * 32 + half * 16;
#pragma unroll
      for (int q = 0; q < 4; ++q) {
        uint4 v = *(const uint4*)(rp + (q << 2));
        a[8*q+0] += bflo(v.x); a[8*q+1] += bfhi(v.x);
        a[8*q+2] += bflo(v.y); a[8*q+3] += bfhi(v.y);
        a[8*q+4] += bflo(v.z); a[8*q+5] += bfhi(v.z);
        a[8*q+6] += bflo(v.w); a[8*q+7] += bfhi(v.w);
      }
    }
    const float inv = 1.0f / 17.0f;
    u32 pk[16];
#pragma unroll
    for (int j = 0; j < 16; ++j)
      pk[j] = packbf(a[2*j] * inv, a[2*j+1] * inv);
#pragma unroll
    for (int q = 0; q < 4; ++q) {
      int byte = r * 128 + ((((half << 6) + (q << 4))) ^ ((r & 7) << 4));
      *(uint4*)(Alds + byte) = make_uint4(pk[4*q], pk[4*q+1], pk[4*q+2], pk[4*q+3]);
    }
  }
  __syncthreads();

  const int lane = tid & 63, wv = tid >> 6;
  const int cl = lane & 15, kg = lane >> 4;

  f32x4 acc[2][8];
#pragma unroll
  for (int rt = 0; rt < 2; ++rt)
#pragma unroll
    for (int ct = 0; ct < 8; ++ct) {
      float bv = b2[(ct << 4) + cl];
      acc[rt][ct] = (f32x4){bv, bv, bv, bv};
    }

#pragma unroll
  for (int ks = 0; ks < 2; ++ks) {
    const int kb = (ks << 6) + (kg << 4);
    bf16x8 af[2];
#pragma unroll
    for (int rt = 0; rt < 2; ++rt) {
      int row = (wv << 5) + (rt << 4) + cl;
      af[rt] = *(const bf16x8*)(Alds + row * 128 + (kb ^ ((row & 7) << 4)));
    }
#pragma unroll
    for (int ct = 0; ct < 8; ++ct) {
      int n = (ct << 4) + cl;
      int byte = n * 128 + (kb ^ ((n & 7) << 4));
      bf16x8 bh = *(const bf16x8*)(Bhi + byte);
      bf16x8 bl = *(const bf16x8*)(Blo + byte);
#pragma unroll
      for (int rt = 0; rt < 2; ++rt) {
        acc[rt][ct] = __builtin_amdgcn_mfma_f32_16x16x32_bf16(af[rt], bh, acc[rt][ct], 0, 0, 0);
        acc[rt][ct] = __builtin_amdgcn_mfma_f32_16x16x32_bf16(af[rt], bl, acc[rt][ct], 0, 0, 0);
      }
    }
  }

  unsigned short* x2h = (unsigned short*)x2;
#pragma unroll
  for (int rt = 0; rt < 2; ++rt)
#pragma unroll
    for (int ct = 0; ct < 8; ++ct) {
      int colg = (ct << 4) + cl;
      int nr0  = node0 + (wv << 5) + (rt << 4) + (kg << 2);
#pragma unroll
      for (int r = 0; r < 4; ++r) {
        float v = fmaxf(acc[rt][ct][r], 0.0f);
        x2h[(size_t)(nr0 + r) * 128 + colg] = (unsigned short)(packbf(v, 0.0f) & 0xFFFFu);
      }
    }
}

// ---------------------------------------------------------------------------
// K3: final linear 128->128 via MFMA, hi/lo-split weights, f32 out.
// ---------------------------------------------------------------------------
__global__ __launch_bounds__(256) void k3_final(
    const u32* __restrict__ x2, const float* __restrict__ Wf,
    const float* __restrict__ bfv, float* __restrict__ out)
{
  __shared__ uint4 AldsV[2048];   // 32 KB
  __shared__ uint4 BhiV[1024];    // 16 KB
  __shared__ uint4 BloV[1024];
  char* Alds = (char*)AldsV; char* Bhi = (char*)BhiV; char* Blo = (char*)BloV;
  const int tid   = threadIdx.x;
  const int node0 = (blockIdx.x >> 1) << 7;
  const int ch0   = (blockIdx.x & 1) << 6;

#pragma unroll
  for (int i = 0; i < 32; ++i) {
    int e = tid + (i << 8);
    int k = e >> 6, n = e & 63;
    float w = Wf[k * 128 + ch0 + n];
    u32 hb = packbf(w, 0.0f) & 0xFFFFu;
    float whi = __uint_as_float(hb << 16);
    u32 lb = packbf(w - whi, 0.0f) & 0xFFFFu;
    int byte = n * 256 + ((2 * k) ^ ((n & 15) << 4));
    *(unsigned short*)(Bhi + byte) = (unsigned short)hb;
    *(unsigned short*)(Blo + byte) = (unsigned short)lb;
  }

  {
    const int r = tid >> 1, half = tid & 1;
    const u32* src = x2 + (size_t)(node0 + r) * 64 + half * 32;
#pragma unroll
    for (int q = 0; q < 8; ++q) {
      uint4 v = *(const uint4*)(src + (q << 2));
      int byte = r * 256 + ((((half << 7) + (q << 4))) ^ ((r & 15) << 4));
      *(uint4*)(Alds + byte) = v;
    }
  }
  __syncthreads();

  const int lane = tid & 63, wv = tid >> 6;
  const int cl = lane & 15, kg = lane >> 4;

  f32x4 acc[2][4];
#pragma unroll
  for (int rt = 0; rt < 2; ++rt)
#pragma unroll
    for (int ct = 0; ct < 4; ++ct) {
      float bv = bfv[ch0 + (ct << 4) + cl];
      acc[rt][ct] = (f32x4){bv, bv, bv, bv};
    }

#pragma unroll
  for (int ks = 0; ks < 4; ++ks) {
    const int kb = (ks << 6) + (kg << 4);
    bf16x8 af[2];
#pragma unroll
    for (int rt = 0; rt < 2; ++rt) {
      int row = (wv << 5) + (rt << 4) + cl;
      af[rt] = *(const bf16x8*)(Alds + row * 256 + (kb ^ ((row & 15) << 4)));
    }
#pragma unroll
    for (int ct = 0; ct < 4; ++ct) {
      int n = (ct << 4) + cl;
      int byte = n * 256 + (kb ^ ((n & 15) << 4));
      bf16x8 bh = *(const bf16x8*)(Bhi + byte);
      bf16x8 bl = *(const bf16x8*)(Blo + byte);
#pragma unroll
      for (int rt = 0; rt < 2; ++rt) {
        acc[rt][ct] = __builtin_amdgcn_mfma_f32_16x16x32_bf16(af[rt], bh, acc[rt][ct], 0, 0, 0);
        acc[rt][ct] = __builtin_amdgcn_mfma_f32_16x16x32_bf16(af[rt], bl, acc[rt][ct], 0, 0, 0);
      }
    }
  }

#pragma unroll
  for (int rt = 0; rt < 2; ++rt)
#pragma unroll
    for (int ct = 0; ct < 4; ++ct) {
      int col = ch0 + (ct << 4) + cl;
      int nr0 = node0 + (wv << 5) + (rt << 4) + (kg << 2);
#pragma unroll
      for (int r = 0; r < 4; ++r)
        out[(size_t)(nr0 + r) * 128 + col] = acc[rt][ct][r];
    }
}

extern "C" void kernel_launch(void* const* d_in, const int* in_sizes, int n_in,
                              void* d_out, int out_size, void* d_ws, size_t ws_size,
                              hipStream_t stream) {
  const float* coords = (const float*)d_in[0];
  const float* W1 = (const float*)d_in[1];
  const float* b1 = (const float*)d_in[2];
  const float* W2 = (const float*)d_in[3];
  const float* b2 = (const float*)d_in[4];
  const float* Wf = (const float*)d_in[5];
  const float* bf = (const float*)d_in[6];
  float* out = (float*)d_out;

  char* ws = (char*)d_ws;
  int* nbr = (int*)ws;                                  //  4 MB: [32,2048,16] i32
  u32* x1  = (u32*)(ws + (size_t)4  * 1024 * 1024);     //  8 MB: [32,2048,64] bf16
  u32* x2  = (u32*)(ws + (size_t)12 * 1024 * 1024);     // 16 MB: [65536,128] bf16

  k1_knn_l1<<<2048, 256, 0, stream>>>(coords, W1, b1, nbr, x1);
  k2_gcn2  <<< 512, 256, 0, stream>>>(x1, nbr, W2, b2, x2);
  k3_final <<<1024, 256, 0, stream>>>(x2, Wf, bf, out);
}